// Round 24
// baseline (64.442 us; speedup 1.0000x reference)
//
#include <hip/hip_runtime.h>
#include <math.h>

#define NR   2048
#define XD   512
#define HID  300
#define BS   256
#define NPAD 320
#define KTOT 1024
#define GSTR 304          // row stride for P0a/P0b (f32)
#define HSTR 304          // row stride for GPBh (ushort)
#define KP   320          // padded k (40 k8-slots; k>=300 exact zeros)
#define NNEG 256          // negpos blocks (1 per CU)

typedef __attribute__((ext_vector_type(8))) short bf16x8;
typedef __attribute__((ext_vector_type(4))) float f32x4;

__device__ __forceinline__ float softplus_f(float x) {
    return fmaxf(x, 0.f) + log1pf(__expf(-fabsf(x)));
}
__device__ __forceinline__ unsigned short f2bf(float f) {
    unsigned int u = __float_as_uint(f);
    u += 0x7FFFu + ((u >> 16) & 1u);   // RNE
    return (unsigned short)(u >> 16);
}
__device__ __forceinline__ float bf2f(unsigned short h) {
    return __uint_as_float((unsigned int)h << 16);
}
// unpack 2 bf16 packed in a u32: lo -> shl, hi -> mask (1 instr each)
__device__ __forceinline__ void unpk(unsigned int u, float& lo, float& hi) {
    lo = __uint_as_float(u << 16);
    hi = __uint_as_float(u & 0xFFFF0000u);
}
// async global->LDS, 16B per lane (dest = wave-uniform base + lane*16)
__device__ __forceinline__ void gload_lds16(const void* g, void* l) {
    __builtin_amdgcn_global_load_lds(
        (const __attribute__((address_space(1))) void*)g,
        (__attribute__((address_space(3))) void*)l, 16, 0, 0);
}

// grid.x = 2048 (Aneg rows) + 2048 (Apos rows) + 320 (Wt tiles)
__global__ __launch_bounds__(256) void convert(
    const float* __restrict__ pl, const float* __restrict__ pg,
    const float* __restrict__ nl, const float* __restrict__ ng,
    const float* __restrict__ W1,
    unsigned short* __restrict__ Aneg, unsigned short* __restrict__ Apos,
    unsigned short* __restrict__ Wt, unsigned int* __restrict__ counter)
{
    const int b = blockIdx.x, tid = threadIdx.x;
    if (b == 0 && tid == 0) *counter = 0u;   // reset ticket each call
    if (b < 4096) {
        const int m = (b < 2048) ? b : b - 2048;
        const float* lo = (b < 2048) ? nl : pl;
        const float* hi = (b < 2048) ? ng : pg;
        unsigned short* dst = (b < 2048) ? Aneg : Apos;
        const int kq = tid * 4;
        const float4 v = (kq < XD) ? *(const float4*)(lo + m * XD + kq)
                                   : *(const float4*)(hi + m * XD + kq - XD);
        ushort4 o;
        o.x = f2bf(v.x); o.y = f2bf(v.y); o.z = f2bf(v.z); o.w = f2bf(v.w);
        *(ushort4*)(dst + m * KTOT + kq) = o;
    } else {
        // W1 [1024][300] -> Wt [320][1024] bf16, zero-padded rows 300..319
        __shared__ unsigned short ts[16][72];
        const int t = b - 4096;
        const int nt = t % 20, kt = t / 20;   // 20 n-tiles x 16 k-tiles
        const int n = nt * 16 + (tid & 15);
        const int kl = tid >> 4;
        #pragma unroll
        for (int j = 0; j < 4; ++j) {
            const int k = kt * 64 + kl * 4 + j;
            ts[tid & 15][kl * 4 + j] = f2bf((n < HID) ? W1[k * HID + n] : 0.f);
        }
        __syncthreads();
        const int nw = tid >> 4, kw = (tid & 15) * 4;
        ushort4 o;
        o.x = ts[nw][kw]; o.y = ts[nw][kw + 1]; o.z = ts[nw][kw + 2]; o.w = ts[nw][kw + 3];
        *(ushort4*)(Wt + (nt * 16 + nw) * KTOT + kt * 64 + kw) = o;
    }
}

// One wave per block, 64x64 tile of 16x16x32 MFMAs (4x4 fragments), K=512.
// grid = 640: job = bid/160, t = bid%160, m0 = (t&31)*64, n0 = (t>>5)*64.
// job 0: LP4h = nl@W1l  -> bf16 [k8 0..39][l 0..2047][8] (k>=300 exact 0)
// job 1: GPBh = ng@W1g + b1 -> bf16 [row][HSTR]
// job 2: P0a = pl@W1l (f32)   job 3: P0b = pg@W1g (f32)
__global__ __launch_bounds__(64) void mfma_gemm(
    const unsigned short* __restrict__ Aneg, const unsigned short* __restrict__ Apos,
    const unsigned short* __restrict__ Wt, const float* __restrict__ b1,
    unsigned short* __restrict__ LP4h, unsigned short* __restrict__ GPBh,
    float* __restrict__ P0a, float* __restrict__ P0b)
{
    const int bid = blockIdx.x;
    const int job = bid / 160, t = bid % 160;
    const int m0 = (t & 31) * 64, n0 = (t >> 5) * 64;
    const int lane = threadIdx.x;
    const int r = lane & 15, g = lane >> 4;

    const unsigned short* A = (job >= 2) ? Apos : Aneg;
    const int kbeg = (job & 1) ? XD : 0;

    const unsigned short* ap[4];
    const unsigned short* bp[4];
    #pragma unroll
    for (int mi = 0; mi < 4; ++mi)
        ap[mi] = A + (m0 + 16 * mi + r) * KTOT + kbeg + 8 * g;
    #pragma unroll
    for (int ni = 0; ni < 4; ++ni)
        bp[ni] = Wt + (n0 + 16 * ni + r) * KTOT + kbeg + 8 * g;

    f32x4 acc[4][4] = {};

    #pragma unroll 4
    for (int k = 0; k < XD; k += 32) {
        bf16x8 a[4], w[4];
        #pragma unroll
        for (int mi = 0; mi < 4; ++mi) a[mi] = *(const bf16x8*)(ap[mi] + k);
        #pragma unroll
        for (int ni = 0; ni < 4; ++ni) w[ni] = *(const bf16x8*)(bp[ni] + k);
        #pragma unroll
        for (int mi = 0; mi < 4; ++mi)
            #pragma unroll
            for (int ni = 0; ni < 4; ++ni)
                acc[mi][ni] = __builtin_amdgcn_mfma_f32_16x16x32_bf16(
                    a[mi], w[ni], acc[mi][ni], 0, 0, 0);
    }

    #pragma unroll
    for (int mi = 0; mi < 4; ++mi) {
        #pragma unroll
        for (int ni = 0; ni < 4; ++ni) {
            const int n = n0 + ni * 16 + r;     // k index (job 0) / col (others)
            const int mb = m0 + mi * 16 + 4 * g;
            const f32x4 v = acc[mi][ni];
            if (job == 0) {
                unsigned short* base = LP4h + ((size_t)(n >> 3) * NR + mb) * 8 + (n & 7);
                base[0]  = f2bf(v[0]); base[8]  = f2bf(v[1]);
                base[16] = f2bf(v[2]); base[24] = f2bf(v[3]);
            } else if (n < HID) {
                if (job == 1) {
                    const float bias = b1[n];
                    #pragma unroll
                    for (int j = 0; j < 4; ++j)
                        GPBh[(size_t)(mb + j) * HSTR + n] = f2bf(v[j] + bias);
                } else {
                    float* out = (job == 2) ? P0a : P0b;
                    #pragma unroll
                    for (int j = 0; j < 4; ++j)
                        out[(size_t)(mb + j) * GSTR + n] = v[j];
                }
            }
        }
    }
}

// 256 blocks x 512 threads (1 block/CU, LDS ~139 KB).
// LP staged via global_load_lds double-buffer: 5 phases x 8 k8 (32 KB each).
// Phase p: issue stage(p+1) async -> compute wave-kh's k8 = 8p+kh from
// buf[p&1] -> __syncthreads() (drains vmcnt -> buf[(p+1)&1] ready).
// acc[8][4] (+q) accumulate across phases; rest identical to R18.
__global__ __launch_bounds__(512, 2) void negpos(
    const unsigned short* __restrict__ LP4h, const unsigned short* __restrict__ GPBh,
    const float* __restrict__ P0a, const float* __restrict__ P0b,
    const float* __restrict__ b1, const float* __restrict__ W2,
    const float* __restrict__ b2,
    float* __restrict__ negE, float* __restrict__ posP,
    unsigned int* __restrict__ counter, float* __restrict__ out)
{
    __shared__ __align__(16) unsigned short lps[2][8][BS][8];  // 64 KB dbuf
    __shared__ __align__(16) float w2s[KP];                    // 1.25 KB
    __shared__ __align__(16) float gbs[8][KP];                 // 10 KB
    __shared__ __align__(16) float pacc[8][BS][8];             // 64 KB
    __shared__ float sC[8];
    __shared__ float red[4][8];
    __shared__ float redp[8];
    __shared__ int sh_last;
    const int tid = threadIdx.x, bid = blockIdx.x;
    const int kh = tid >> 6, lh = tid & 63;
    const float b2v = b2[0];
    const int chunk = bid >> 5, g0 = (bid & 31) * 8;
    const size_t cb = (size_t)chunk * BS;

    // gbs (f32 from bf16) + w2s (0.5*W2, zero-padded)
    const unsigned short* gpb = GPBh + (cb + g0) * HSTR;
    if (tid < KP) {
        const bool v = tid < HID;
        w2s[tid] = v ? 0.5f * W2[tid] : 0.f;
        #pragma unroll
        for (int g = 0; g < 8; ++g)
            gbs[g][tid] = v ? bf2f(gpb[g * HSTR + tid]) : 0.f;
    }

    // ---- stage phase 0 (k8 0..7) into lps[0] ----
    #pragma unroll
    for (int i = 0; i < 4; ++i) {
        const int c = i * 512 + tid;
        const int k8l = c >> 8, l = c & 255;
        gload_lds16(LP4h + ((size_t)k8l * NR + cb + l) * 8,
                    &lps[0][k8l][l][0]);
    }
    __syncthreads();   // gbs/w2s + phase-0 staging complete

    // sC[g] = sum_k w'_k g[g][k] ; wave kh handles g-row kh (padded zeros)
    {
        float c = 0.f;
        #pragma unroll
        for (int h = 0; h < 2; ++h) {
            const int k4 = lh + 64 * h;
            if (k4 < 80) {
                const float4 g4 = *(const float4*)&gbs[kh][k4 * 4];
                const float4 w4 = *(const float4*)&w2s[k4 * 4];
                c += g4.x * w4.x + g4.y * w4.y + g4.z * w4.z + g4.w * w4.w;
            }
        }
        #pragma unroll
        for (int o = 32; o > 0; o >>= 1) c += __shfl_xor(c, o);
        if (lh == 0) sC[kh] = c;
    }

    float acc[8][4];      // [gt][j]
    float q[4] = {0.f, 0.f, 0.f, 0.f};
    #pragma unroll
    for (int gt = 0; gt < 8; ++gt)
        #pragma unroll
        for (int j = 0; j < 4; ++j) acc[gt][j] = 0.f;

    #pragma unroll
    for (int p = 0; p < 5; ++p) {
        // issue next phase's staging (async; lands by the barrier below)
        if (p < 4) {
            #pragma unroll
            for (int i = 0; i < 4; ++i) {
                const int c = i * 512 + tid;
                const int k8l = c >> 8, l = c & 255;
                gload_lds16(LP4h + ((size_t)((p + 1) * 8 + k8l) * NR + cb + l) * 8,
                            &lps[(p + 1) & 1][k8l][l][0]);
            }
        }
        // compute this wave's k8 slot from the current buffer
        const int k8g = p * 8 + kh;
        const uint4 u0 = *(const uint4*)&lps[p & 1][kh][lh][0];
        const uint4 u1 = *(const uint4*)&lps[p & 1][kh][lh + 64][0];
        const uint4 u2 = *(const uint4*)&lps[p & 1][kh][lh + 128][0];
        const uint4 u3 = *(const uint4*)&lps[p & 1][kh][lh + 192][0];
        const float4 wa = *(const float4*)&w2s[k8g * 8];
        const float4 wb = *(const float4*)&w2s[k8g * 8 + 4];
        float fv[4][8];
        unpk(u0.x, fv[0][0], fv[0][1]); unpk(u0.y, fv[0][2], fv[0][3]);
        unpk(u0.z, fv[0][4], fv[0][5]); unpk(u0.w, fv[0][6], fv[0][7]);
        unpk(u1.x, fv[1][0], fv[1][1]); unpk(u1.y, fv[1][2], fv[1][3]);
        unpk(u1.z, fv[1][4], fv[1][5]); unpk(u1.w, fv[1][6], fv[1][7]);
        unpk(u2.x, fv[2][0], fv[2][1]); unpk(u2.y, fv[2][2], fv[2][3]);
        unpk(u2.z, fv[2][4], fv[2][5]); unpk(u2.w, fv[2][6], fv[2][7]);
        unpk(u3.x, fv[3][0], fv[3][1]); unpk(u3.y, fv[3][2], fv[3][3]);
        unpk(u3.z, fv[3][4], fv[3][5]); unpk(u3.w, fv[3][6], fv[3][7]);
        #pragma unroll
        for (int j = 0; j < 4; ++j) {
            q[j] = fmaf(wa.x, fv[j][0], q[j]); q[j] = fmaf(wa.y, fv[j][1], q[j]);
            q[j] = fmaf(wa.z, fv[j][2], q[j]); q[j] = fmaf(wa.w, fv[j][3], q[j]);
            q[j] = fmaf(wb.x, fv[j][4], q[j]); q[j] = fmaf(wb.y, fv[j][5], q[j]);
            q[j] = fmaf(wb.z, fv[j][6], q[j]); q[j] = fmaf(wb.w, fv[j][7], q[j]);
        }
        #pragma unroll
        for (int gt = 0; gt < 8; ++gt) {
            const float4 ga = *(const float4*)&gbs[gt][k8g * 8];
            const float4 gb = *(const float4*)&gbs[gt][k8g * 8 + 4];
            #pragma unroll
            for (int j = 0; j < 4; ++j) {
                acc[gt][j] = fmaf(fabsf(ga.x + fv[j][0]), wa.x, acc[gt][j]);
                acc[gt][j] = fmaf(fabsf(ga.y + fv[j][1]), wa.y, acc[gt][j]);
                acc[gt][j] = fmaf(fabsf(ga.z + fv[j][2]), wa.z, acc[gt][j]);
                acc[gt][j] = fmaf(fabsf(ga.w + fv[j][3]), wa.w, acc[gt][j]);
                acc[gt][j] = fmaf(fabsf(gb.x + fv[j][4]), wb.x, acc[gt][j]);
                acc[gt][j] = fmaf(fabsf(gb.y + fv[j][5]), wb.y, acc[gt][j]);
                acc[gt][j] = fmaf(fabsf(gb.z + fv[j][6]), wb.z, acc[gt][j]);
                acc[gt][j] = fmaf(fabsf(gb.w + fv[j][7]), wb.w, acc[gt][j]);
            }
        }
        __syncthreads();   // buf reads done + next buf staged
    }

    #pragma unroll
    for (int j = 0; j < 4; ++j) {
        *(float4*)&pacc[kh][lh + 64 * j][0] =
            make_float4(acc[0][j] + q[j], acc[1][j] + q[j],
                        acc[2][j] + q[j], acc[3][j] + q[j]);
        *(float4*)&pacc[kh][lh + 64 * j][4] =
            make_float4(acc[4][j] + q[j], acc[5][j] + q[j],
                        acc[6][j] + q[j], acc[7][j] + q[j]);
    }
    __syncthreads();   // pacc + sC ready

    // combine: thread tid<256 = l; s[gt] = sC[gt] + sum_kh pacc[kh][l][gt]
    if (tid < 256) {
        float s[8];
        #pragma unroll
        for (int gt = 0; gt < 8; ++gt) s[gt] = sC[gt];
        #pragma unroll
        for (int k = 0; k < 8; ++k) {
            const float4 p0 = *(const float4*)&pacc[k][tid][0];
            const float4 p1 = *(const float4*)&pacc[k][tid][4];
            s[0] += p0.x; s[1] += p0.y; s[2] += p0.z; s[3] += p0.w;
            s[4] += p1.x; s[5] += p1.y; s[6] += p1.z; s[7] += p1.w;
        }
        const int wid = tid >> 6;
        #pragma unroll
        for (int gt = 0; gt < 8; ++gt) {
            float v = __expf(softplus_f(s[gt] + b2v));
            #pragma unroll
            for (int o = 32; o > 0; o >>= 1) v += __shfl_xor(v, o);
            if ((tid & 63) == 0) red[wid][gt] = v;
        }
    }
    __syncthreads();
    if (tid == 0) {
        #pragma unroll
        for (int gt = 0; gt < 8; ++gt)
            negE[bid * 8 + gt] = red[0][gt] + red[1][gt] + red[2][gt] + red[3][gt];
    }

    // ---- positive term: wave kh handles row bid*8 + kh ----
    {
        const int row = bid * 8 + kh;
        const float4* ra = (const float4*)(P0a + (size_t)row * GSTR);
        const float4* rb = (const float4*)(P0b + (size_t)row * GSTR);
        float d = 0.f;
        #pragma unroll
        for (int h = 0; h < 2; ++h) {
            const int k4 = lh + 64 * h;
            if (k4 < 75) {
                const float4 aa = ra[k4], bb4 = rb[k4];
                const float4 bb = *(const float4*)(b1 + k4 * 4);
                const float4 wv = *(const float4*)(W2 + k4 * 4);
                d += fmaxf(aa.x + bb4.x + bb.x, 0.f) * wv.x
                   + fmaxf(aa.y + bb4.y + bb.y, 0.f) * wv.y
                   + fmaxf(aa.z + bb4.z + bb.z, 0.f) * wv.z
                   + fmaxf(aa.w + bb4.w + bb.w, 0.f) * wv.w;
            }
        }
        #pragma unroll
        for (int o = 32; o > 0; o >>= 1) d += __shfl_xor(d, o);
        if (lh == 0) redp[kh] = softplus_f(d + b2v);
    }
    __syncthreads();

    // ---- last-block finalize (device-scope ticket over 256 blocks) ----
    if (tid == 0) {
        posP[bid] = redp[0] + redp[1] + redp[2] + redp[3]
                  + redp[4] + redp[5] + redp[6] + redp[7];
        __threadfence();
        const unsigned t = atomicAdd(counter, 1u);
        sh_last = (t == NNEG - 1) ? 1 : 0;
    }
    __syncthreads();
    if (sh_last) {
        __threadfence();
        const volatile float* ne = (const volatile float*)negE;
        const volatile float* pp = (const volatile float*)posP;
        float v = 0.f;
        for (int i = tid; i < 2048; i += 512)
            v += __logf(ne[i]);
        if (tid < NNEG) v -= pp[tid];
        #pragma unroll
        for (int o = 32; o > 0; o >>= 1) v += __shfl_xor(v, o);
        if (lh == 0) redp[kh] = v;
        __syncthreads();
        if (tid == 0)
            out[0] = (redp[0] + redp[1] + redp[2] + redp[3]
                    + redp[4] + redp[5] + redp[6] + redp[7]) * (1.f / 2048.f);
    }
}

extern "C" void kernel_launch(void* const* d_in, const int* in_sizes, int n_in,
                              void* d_out, int out_size, void* d_ws, size_t ws_size,
                              hipStream_t stream)
{
    const float* pl = (const float*)d_in[0];
    const float* pg = (const float*)d_in[1];
    const float* nl = (const float*)d_in[2];
    const float* ng = (const float*)d_in[3];
    const float* W1 = (const float*)d_in[4];
    const float* b1 = (const float*)d_in[5];
    const float* W2 = (const float*)d_in[6];
    const float* b2 = (const float*)d_in[7];

    char* ws = (char*)d_ws;
    unsigned short* Aneg = (unsigned short*)(ws);                 // 4 MB
    unsigned short* Apos = (unsigned short*)(ws + (4u << 20));    // 4 MB
    unsigned short* Wt   = (unsigned short*)(ws + (8u << 20));    // 640 KB
    unsigned short* LP4h = (unsigned short*)(ws + (9u << 20));    // 1.31 MB
    unsigned short* GPBh = (unsigned short*)(ws + (11u << 20));   // 1.22 MB
    float* P0a  = (float*)(ws + (13u << 20));                     // 2.49 MB
    float* P0b  = (float*)(ws + (16u << 20));                     // 2.49 MB
    float* negE = (float*)(ws + (19u << 20));                     // 2048 f
    float* posP = negE + 2048;                                    // 256 f
    unsigned int* counter = (unsigned int*)(ws + (19u << 20) + 65536);
    float* out  = (float*)d_out;

    hipLaunchKernelGGL(convert, dim3(4096 + 320), dim3(256), 0, stream,
                       pl, pg, nl, ng, W1, Aneg, Apos, Wt, counter);
    hipLaunchKernelGGL(mfma_gemm, dim3(640), dim3(64), 0, stream,
                       Aneg, Apos, Wt, b1, LP4h, GPBh, P0a, P0b);
    hipLaunchKernelGGL(negpos, dim3(NNEG), dim3(512), 0, stream,
                       LP4h, GPBh, P0a, P0b, b1, W2, b2, negE, posP, counter, out);
}

// Round 25
// 53.924 us; speedup vs baseline: 1.1950x; 1.1950x over previous
//
#include <hip/hip_runtime.h>
#include <math.h>

#define NR   2048
#define XD   512
#define HID  300
#define BS   256
#define NPAD 320
#define KTOT 1024
#define GSTR 304          // row stride for P0a/P0b (f32)
#define HSTR 304          // row stride for GPBh (ushort)
#define KP   320          // padded k (40 k8-slots; k>=300 exact zeros)
#define NNEG 256          // negpos blocks (1 per CU)
#define BM   128
#define BN   64
#define BK   64
#define LDA  72           // padded LDS row stride (halfwords): 144B = 9x16B
#define NGB  320          // gemm grid: 4 jobs x 16 mt x 5 nt

typedef __attribute__((ext_vector_type(8))) short bf16x8;
typedef __attribute__((ext_vector_type(4))) float f32x4;

__device__ __forceinline__ float softplus_f(float x) {
    return fmaxf(x, 0.f) + log1pf(__expf(-fabsf(x)));
}
__device__ __forceinline__ unsigned short f2bf(float f) {
    unsigned int u = __float_as_uint(f);
    u += 0x7FFFu + ((u >> 16) & 1u);   // RNE
    return (unsigned short)(u >> 16);
}
__device__ __forceinline__ float bf2f(unsigned short h) {
    return __uint_as_float((unsigned int)h << 16);
}
// unpack 2 bf16 packed in a u32: lo -> shl, hi -> mask (1 instr each)
__device__ __forceinline__ void unpk(unsigned int u, float& lo, float& hi) {
    lo = __uint_as_float(u << 16);
    hi = __uint_as_float(u & 0xFFFF0000u);
}
// async global->LDS, 16B per lane (dest = wave-uniform base + lane*16)
__device__ __forceinline__ void gload_lds16(const void* g, void* l) {
    __builtin_amdgcn_global_load_lds(
        (const __attribute__((address_space(1))) void*)g,
        (__attribute__((address_space(3))) void*)l, 16, 0, 0);
}

// grid.x = 2048 (Aneg rows) + 2048 (Apos rows) + 320 (Wt tiles)
__global__ __launch_bounds__(256) void convert(
    const float* __restrict__ pl, const float* __restrict__ pg,
    const float* __restrict__ nl, const float* __restrict__ ng,
    const float* __restrict__ W1,
    unsigned short* __restrict__ Aneg, unsigned short* __restrict__ Apos,
    unsigned short* __restrict__ Wt, unsigned int* __restrict__ counter)
{
    const int b = blockIdx.x, tid = threadIdx.x;
    if (b == 0 && tid == 0) *counter = 0u;   // reset ticket each call
    if (b < 4096) {
        const int m = (b < 2048) ? b : b - 2048;
        const float* lo = (b < 2048) ? nl : pl;
        const float* hi = (b < 2048) ? ng : pg;
        unsigned short* dst = (b < 2048) ? Aneg : Apos;
        const int kq = tid * 4;
        const float4 v = (kq < XD) ? *(const float4*)(lo + m * XD + kq)
                                   : *(const float4*)(hi + m * XD + kq - XD);
        ushort4 o;
        o.x = f2bf(v.x); o.y = f2bf(v.y); o.z = f2bf(v.z); o.w = f2bf(v.w);
        *(ushort4*)(dst + m * KTOT + kq) = o;
    } else {
        // W1 [1024][300] -> Wt [320][1024] bf16, zero-padded rows 300..319
        __shared__ unsigned short ts[16][72];
        const int t = b - 4096;
        const int nt = t % 20, kt = t / 20;   // 20 n-tiles x 16 k-tiles
        const int n = nt * 16 + (tid & 15);
        const int kl = tid >> 4;
        #pragma unroll
        for (int j = 0; j < 4; ++j) {
            const int k = kt * 64 + kl * 4 + j;
            ts[tid & 15][kl * 4 + j] = f2bf((n < HID) ? W1[k * HID + n] : 0.f);
        }
        __syncthreads();
        const int nw = tid >> 4, kw = (tid & 15) * 4;
        ushort4 o;
        o.x = ts[nw][kw]; o.y = ts[nw][kw + 1]; o.z = ts[nw][kw + 2]; o.w = ts[nw][kw + 3];
        *(ushort4*)(Wt + (nt * 16 + nw) * KTOT + kt * 64 + kw) = o;
    }
}

// 4-wave block, 128x64 tile, K=512 in BK=64 double-buffered LDS stages
// (global_load_lds, padded LDS rows: stride 72 hw = 144B -> 2-way-free b128
// frag reads, 16B aligned). Wave w computes rows [w*32, w*32+32).
// grid = 320: job = bid/80, t = bid%80, m0 = (t/5)*128, n0 = (t%5)*64.
// job 0: LP4h = nl@W1l  -> bf16 [k8 0..39][l 0..2047][8] (k>=300 exact 0)
// job 1: GPBh = ng@W1g + b1 -> bf16 [row][HSTR]
// job 2: P0a = pl@W1l (f32)   job 3: P0b = pg@W1g (f32)
__global__ __launch_bounds__(256, 2) void mfma_gemm(
    const unsigned short* __restrict__ Aneg, const unsigned short* __restrict__ Apos,
    const unsigned short* __restrict__ Wt, const float* __restrict__ b1,
    unsigned short* __restrict__ LP4h, unsigned short* __restrict__ GPBh,
    float* __restrict__ P0a, float* __restrict__ P0b)
{
    __shared__ __align__(16) unsigned short As[2][BM * LDA];   // 36.9 KB
    __shared__ __align__(16) unsigned short Ws[2][BN * LDA];   // 18.4 KB
    const int bid = blockIdx.x;
    const int job = bid / 80, t = bid % 80;
    const int m0 = (t / 5) * BM, n0 = (t % 5) * BN;
    const int tid = threadIdx.x;
    const int w = tid >> 6, lane = tid & 63;
    const int r = lane & 15, g = lane >> 4;

    const unsigned short* A = (job >= 2) ? Apos : Aneg;
    const int kbeg = (job & 1) ? XD : 0;

    // stage BK=64 slab into buffer buf: A 128 rows x 9 chunks (chunk 8 = pad,
    // filled from chunk 0 - never read), W 64 rows x 9 chunks.
    auto stage = [&](int buf, int kc) {
        #pragma unroll
        for (int i = 0; i < 5; ++i) {
            const int d = i * 256 + tid;
            if (d < BM * 9) {
                const int row = d / 9, c = d % 9;
                const int sk = (c < 8) ? c * 8 : 0;
                gload_lds16(A + (size_t)(m0 + row) * KTOT + kbeg + kc + sk,
                            &As[buf][(size_t)d * 8]);
            }
        }
        #pragma unroll
        for (int i = 0; i < 3; ++i) {
            const int d = i * 256 + tid;
            if (d < BN * 9) {
                const int row = d / 9, c = d % 9;
                const int sk = (c < 8) ? c * 8 : 0;
                gload_lds16(Wt + (size_t)(n0 + row) * KTOT + kbeg + kc + sk,
                            &Ws[buf][(size_t)d * 8]);
            }
        }
    };

    f32x4 acc[2][4] = {};

    stage(0, 0);
    __syncthreads();

    for (int kc = 0; kc < 8; ++kc) {
        const int cur = kc & 1;
        if (kc < 7) stage(cur ^ 1, (kc + 1) * BK);
        #pragma unroll
        for (int ks = 0; ks < 2; ++ks) {
            bf16x8 a[2], wv[4];
            #pragma unroll
            for (int mi = 0; mi < 2; ++mi)
                a[mi] = *(const bf16x8*)&As[cur][(w * 32 + mi * 16 + r) * LDA + ks * 32 + g * 8];
            #pragma unroll
            for (int ni = 0; ni < 4; ++ni)
                wv[ni] = *(const bf16x8*)&Ws[cur][(ni * 16 + r) * LDA + ks * 32 + g * 8];
            #pragma unroll
            for (int mi = 0; mi < 2; ++mi)
                #pragma unroll
                for (int ni = 0; ni < 4; ++ni)
                    acc[mi][ni] = __builtin_amdgcn_mfma_f32_16x16x32_bf16(
                        a[mi], wv[ni], acc[mi][ni], 0, 0, 0);
        }
        __syncthreads();   // buf reads done + next buf staged
    }

    #pragma unroll
    for (int mi = 0; mi < 2; ++mi) {
        #pragma unroll
        for (int ni = 0; ni < 4; ++ni) {
            const int n = n0 + ni * 16 + r;     // k index (job 0) / col (others)
            const int mb = m0 + w * 32 + mi * 16 + 4 * g;
            const f32x4 v = acc[mi][ni];
            if (job == 0) {
                unsigned short* base = LP4h + ((size_t)(n >> 3) * NR + mb) * 8 + (n & 7);
                base[0]  = f2bf(v[0]); base[8]  = f2bf(v[1]);
                base[16] = f2bf(v[2]); base[24] = f2bf(v[3]);
            } else if (n < HID) {
                if (job == 1) {
                    const float bias = b1[n];
                    #pragma unroll
                    for (int j = 0; j < 4; ++j)
                        GPBh[(size_t)(mb + j) * HSTR + n] = f2bf(v[j] + bias);
                } else {
                    float* out = (job == 2) ? P0a : P0b;
                    #pragma unroll
                    for (int j = 0; j < 4; ++j)
                        out[(size_t)(mb + j) * GSTR + n] = v[j];
                }
            }
        }
    }
}

// 256 blocks x 512 threads (1 block/CU). R18-proven structure:
//  neg unit = (chunk = bid>>5, 8 g-rows = (bid&31)*8). Waves = k-eighths
//  (kh = tid>>6, 5 k8-slots each, compile-time), lane lh = tid&63, L=4
//  l-streams. LP read DIRECTLY from global bf16 (uint4); unpack via u32
//  shl/mask. w*relu(t) = w't + w'|t| (w'=w/2); k>=300 slots contribute 0.
//  pos rows: wave kh handles row bid*8+kh. Last block (ticket) finalizes.
__global__ __launch_bounds__(512, 2) void negpos(
    const unsigned short* __restrict__ LP4h, const unsigned short* __restrict__ GPBh,
    const float* __restrict__ P0a, const float* __restrict__ P0b,
    const float* __restrict__ b1, const float* __restrict__ W2,
    const float* __restrict__ b2,
    float* __restrict__ negE, float* __restrict__ posP,
    unsigned int* __restrict__ counter, float* __restrict__ out)
{
    __shared__ __align__(16) float w2s[KP];           // 1.25 KB
    __shared__ __align__(16) float gbs[8][KP];        // 10 KB
    __shared__ __align__(16) float pacc[8][BS][8];    // 64 KB
    __shared__ float sC[8];
    __shared__ float red[4][8];
    __shared__ float redp[8];
    __shared__ int sh_last;
    const int tid = threadIdx.x, bid = blockIdx.x;
    const int kh = tid >> 6, lh = tid & 63;
    const float b2v = b2[0];
    const int chunk = bid >> 5, g0 = (bid & 31) * 8;
    const size_t cb = (size_t)chunk * BS;

    // gbs (f32 from bf16) + w2s (0.5*W2, zero-padded)
    const unsigned short* gpb = GPBh + (cb + g0) * HSTR;
    if (tid < KP) {
        const bool v = tid < HID;
        w2s[tid] = v ? 0.5f * W2[tid] : 0.f;
        #pragma unroll
        for (int g = 0; g < 8; ++g)
            gbs[g][tid] = v ? bf2f(gpb[g * HSTR + tid]) : 0.f;
    }
    __syncthreads();

    // sC[g] = sum_k w'_k g[g][k] ; wave kh handles g-row kh (padded zeros)
    {
        float c = 0.f;
        #pragma unroll
        for (int h = 0; h < 2; ++h) {
            const int k4 = lh + 64 * h;
            if (k4 < 80) {
                const float4 g4 = *(const float4*)&gbs[kh][k4 * 4];
                const float4 w4 = *(const float4*)&w2s[k4 * 4];
                c += g4.x * w4.x + g4.y * w4.y + g4.z * w4.z + g4.w * w4.w;
            }
        }
        #pragma unroll
        for (int o = 32; o > 0; o >>= 1) c += __shfl_xor(c, o);
        if (lh == 0) sC[kh] = c;
    }

    // main loop: 5 k8-slots per wave, compile-time; direct bf16 global reads
    float acc[8][4];      // [gt][j]
    float q[4] = {0.f, 0.f, 0.f, 0.f};
    #pragma unroll
    for (int gt = 0; gt < 8; ++gt)
        #pragma unroll
        for (int j = 0; j < 4; ++j) acc[gt][j] = 0.f;

    #pragma unroll
    for (int i = 0; i < 5; ++i) {
        const int k8 = 5 * kh + i;
        uint4 u0 = *(const uint4*)(LP4h + ((size_t)k8 * NR + cb + lh)       * 8);
        uint4 u1 = *(const uint4*)(LP4h + ((size_t)k8 * NR + cb + lh + 64)  * 8);
        uint4 u2 = *(const uint4*)(LP4h + ((size_t)k8 * NR + cb + lh + 128) * 8);
        uint4 u3 = *(const uint4*)(LP4h + ((size_t)k8 * NR + cb + lh + 192) * 8);
        const float4 wa = *(const float4*)&w2s[k8 * 8];
        const float4 wb = *(const float4*)&w2s[k8 * 8 + 4];
        float fv[4][8];
        unpk(u0.x, fv[0][0], fv[0][1]); unpk(u0.y, fv[0][2], fv[0][3]);
        unpk(u0.z, fv[0][4], fv[0][5]); unpk(u0.w, fv[0][6], fv[0][7]);
        unpk(u1.x, fv[1][0], fv[1][1]); unpk(u1.y, fv[1][2], fv[1][3]);
        unpk(u1.z, fv[1][4], fv[1][5]); unpk(u1.w, fv[1][6], fv[1][7]);
        unpk(u2.x, fv[2][0], fv[2][1]); unpk(u2.y, fv[2][2], fv[2][3]);
        unpk(u2.z, fv[2][4], fv[2][5]); unpk(u2.w, fv[2][6], fv[2][7]);
        unpk(u3.x, fv[3][0], fv[3][1]); unpk(u3.y, fv[3][2], fv[3][3]);
        unpk(u3.z, fv[3][4], fv[3][5]); unpk(u3.w, fv[3][6], fv[3][7]);
        #pragma unroll
        for (int j = 0; j < 4; ++j) {
            q[j] = fmaf(wa.x, fv[j][0], q[j]); q[j] = fmaf(wa.y, fv[j][1], q[j]);
            q[j] = fmaf(wa.z, fv[j][2], q[j]); q[j] = fmaf(wa.w, fv[j][3], q[j]);
            q[j] = fmaf(wb.x, fv[j][4], q[j]); q[j] = fmaf(wb.y, fv[j][5], q[j]);
            q[j] = fmaf(wb.z, fv[j][6], q[j]); q[j] = fmaf(wb.w, fv[j][7], q[j]);
        }
        #pragma unroll
        for (int gt = 0; gt < 8; ++gt) {
            const float4 ga = *(const float4*)&gbs[gt][k8 * 8];
            const float4 gb = *(const float4*)&gbs[gt][k8 * 8 + 4];
            #pragma unroll
            for (int j = 0; j < 4; ++j) {
                acc[gt][j] = fmaf(fabsf(ga.x + fv[j][0]), wa.x, acc[gt][j]);
                acc[gt][j] = fmaf(fabsf(ga.y + fv[j][1]), wa.y, acc[gt][j]);
                acc[gt][j] = fmaf(fabsf(ga.z + fv[j][2]), wa.z, acc[gt][j]);
                acc[gt][j] = fmaf(fabsf(ga.w + fv[j][3]), wa.w, acc[gt][j]);
                acc[gt][j] = fmaf(fabsf(gb.x + fv[j][4]), wb.x, acc[gt][j]);
                acc[gt][j] = fmaf(fabsf(gb.y + fv[j][5]), wb.y, acc[gt][j]);
                acc[gt][j] = fmaf(fabsf(gb.z + fv[j][6]), wb.z, acc[gt][j]);
                acc[gt][j] = fmaf(fabsf(gb.w + fv[j][7]), wb.w, acc[gt][j]);
            }
        }
    }

    #pragma unroll
    for (int j = 0; j < 4; ++j) {
        *(float4*)&pacc[kh][lh + 64 * j][0] =
            make_float4(acc[0][j] + q[j], acc[1][j] + q[j],
                        acc[2][j] + q[j], acc[3][j] + q[j]);
        *(float4*)&pacc[kh][lh + 64 * j][4] =
            make_float4(acc[4][j] + q[j], acc[5][j] + q[j],
                        acc[6][j] + q[j], acc[7][j] + q[j]);
    }
    __syncthreads();   // pacc + sC ready

    // combine: thread tid<256 = l; s[gt] = sC[gt] + sum_kh pacc[kh][l][gt]
    if (tid < 256) {
        float s[8];
        #pragma unroll
        for (int gt = 0; gt < 8; ++gt) s[gt] = sC[gt];
        #pragma unroll
        for (int k = 0; k < 8; ++k) {
            const float4 p0 = *(const float4*)&pacc[k][tid][0];
            const float4 p1 = *(const float4*)&pacc[k][tid][4];
            s[0] += p0.x; s[1] += p0.y; s[2] += p0.z; s[3] += p0.w;
            s[4] += p1.x; s[5] += p1.y; s[6] += p1.z; s[7] += p1.w;
        }
        const int wid = tid >> 6;
        #pragma unroll
        for (int gt = 0; gt < 8; ++gt) {
            float v = __expf(softplus_f(s[gt] + b2v));
            #pragma unroll
            for (int o = 32; o > 0; o >>= 1) v += __shfl_xor(v, o);
            if ((tid & 63) == 0) red[wid][gt] = v;
        }
    }
    __syncthreads();
    if (tid == 0) {
        #pragma unroll
        for (int gt = 0; gt < 8; ++gt)
            negE[bid * 8 + gt] = red[0][gt] + red[1][gt] + red[2][gt] + red[3][gt];
    }

    // ---- positive term: wave kh handles row bid*8 + kh ----
    {
        const int row = bid * 8 + kh;
        const float4* ra = (const float4*)(P0a + (size_t)row * GSTR);
        const float4* rb = (const float4*)(P0b + (size_t)row * GSTR);
        float d = 0.f;
        #pragma unroll
        for (int h = 0; h < 2; ++h) {
            const int k4 = lh + 64 * h;
            if (k4 < 75) {
                const float4 aa = ra[k4], bb4 = rb[k4];
                const float4 bb = *(const float4*)(b1 + k4 * 4);
                const float4 wv = *(const float4*)(W2 + k4 * 4);
                d += fmaxf(aa.x + bb4.x + bb.x, 0.f) * wv.x
                   + fmaxf(aa.y + bb4.y + bb.y, 0.f) * wv.y
                   + fmaxf(aa.z + bb4.z + bb.z, 0.f) * wv.z
                   + fmaxf(aa.w + bb4.w + bb.w, 0.f) * wv.w;
            }
        }
        #pragma unroll
        for (int o = 32; o > 0; o >>= 1) d += __shfl_xor(d, o);
        if (lh == 0) redp[kh] = softplus_f(d + b2v);
    }
    __syncthreads();

    // ---- last-block finalize (device-scope ticket over 256 blocks) ----
    if (tid == 0) {
        posP[bid] = redp[0] + redp[1] + redp[2] + redp[3]
                  + redp[4] + redp[5] + redp[6] + redp[7];
        __threadfence();
        const unsigned t = atomicAdd(counter, 1u);
        sh_last = (t == NNEG - 1) ? 1 : 0;
    }
    __syncthreads();
    if (sh_last) {
        __threadfence();
        const volatile float* ne = (const volatile float*)negE;
        const volatile float* pp = (const volatile float*)posP;
        float v = 0.f;
        for (int i = tid; i < 2048; i += 512)
            v += __logf(ne[i]);
        if (tid < NNEG) v -= pp[tid];
        #pragma unroll
        for (int o = 32; o > 0; o >>= 1) v += __shfl_xor(v, o);
        if (lh == 0) redp[kh] = v;
        __syncthreads();
        if (tid == 0)
            out[0] = (redp[0] + redp[1] + redp[2] + redp[3]
                    + redp[4] + redp[5] + redp[6] + redp[7]) * (1.f / 2048.f);
    }
}

extern "C" void kernel_launch(void* const* d_in, const int* in_sizes, int n_in,
                              void* d_out, int out_size, void* d_ws, size_t ws_size,
                              hipStream_t stream)
{
    const float* pl = (const float*)d_in[0];
    const float* pg = (const float*)d_in[1];
    const float* nl = (const float*)d_in[2];
    const float* ng = (const float*)d_in[3];
    const float* W1 = (const float*)d_in[4];
    const float* b1 = (const float*)d_in[5];
    const float* W2 = (const float*)d_in[6];
    const float* b2 = (const float*)d_in[7];

    char* ws = (char*)d_ws;
    unsigned short* Aneg = (unsigned short*)(ws);                 // 4 MB
    unsigned short* Apos = (unsigned short*)(ws + (4u << 20));    // 4 MB
    unsigned short* Wt   = (unsigned short*)(ws + (8u << 20));    // 640 KB
    unsigned short* LP4h = (unsigned short*)(ws + (9u << 20));    // 1.31 MB
    unsigned short* GPBh = (unsigned short*)(ws + (11u << 20));   // 1.22 MB
    float* P0a  = (float*)(ws + (13u << 20));                     // 2.49 MB
    float* P0b  = (float*)(ws + (16u << 20));                     // 2.49 MB
    float* negE = (float*)(ws + (19u << 20));                     // 2048 f
    float* posP = negE + 2048;                                    // 256 f
    unsigned int* counter = (unsigned int*)(ws + (19u << 20) + 65536);
    float* out  = (float*)d_out;

    hipLaunchKernelGGL(convert, dim3(4096 + 320), dim3(256), 0, stream,
                       pl, pg, nl, ng, W1, Aneg, Apos, Wt, counter);
    hipLaunchKernelGGL(mfma_gemm, dim3(NGB), dim3(256), 0, stream,
                       Aneg, Apos, Wt, b1, LP4h, GPBh, P0a, P0b);
    hipLaunchKernelGGL(negpos, dim3(NNEG), dim3(512), 0, stream,
                       LP4h, GPBh, P0a, P0b, b1, W2, b2, negE, posP, counter, out);
}